// Round 16
// baseline (210.688 us; speedup 1.0000x reference)
//
#include <hip/hip_runtime.h>

// Problem constants (match reference)
#define N_NODES 100000
#define N_EDGES 1200000
#define DIM     64
#define BGRAPHS 1000
#define NCLASS  10
#define BN_EPS  1e-5f

// CSR-build partition constants
#define NBUCK   256            // coarse buckets
#define NPB     391            // nodes per bucket (256*391 = 100096 >= N)
#define MAGIC   10984572u      // ceil(2^32/391): bucket = umulhi(d, MAGIC)
#define CHUNK   4096           // edges per partition block (32KB int2 staging)
#define NBLK_P  293            // ceil(E / CHUNK)
#define BCAP    8192           // fixed per-bucket region capacity (proven >= max bucket size)
#define NB_G    1563           // ceil(N/64) GEMM blocks in prep

typedef __attribute__((ext_vector_type(8))) short   bfx8;   // 8 bf16 MFMA A/B frag
typedef __attribute__((ext_vector_type(4))) float   f32x4;  // MFMA C/D frag
typedef __attribute__((ext_vector_type(8))) unsigned short u16x8;

__device__ __forceinline__ unsigned short f2bf(float f) {
    unsigned u = __builtin_bit_cast(unsigned, f);
    unsigned r = (u + 0x7FFFu + ((u >> 16) & 1u)) >> 16;   // RNE
    return (unsigned short)r;
}
__device__ __forceinline__ float bf2f(unsigned short h) {
    unsigned u = ((unsigned)h) << 16;
    return __builtin_bit_cast(float, u);
}

// B-fragment loader: element j = W[(kt*32 + q*8 + j)][col]  (fp32 W -> bf16)
__device__ __forceinline__ bfx8 load_wfrag(const float* __restrict__ W, int kt, int q, int col) {
    bfx8 f;
    #pragma unroll
    for (int j = 0; j < 8; ++j)
        f[j] = (short)f2bf(W[(kt * 32 + q * 8 + j) * 64 + col]);
    return f;
}

// ---------------------------------------------------------------------------
// Quad-accumulator gather core: self + 4 independent neighbor chains keep
// 4 row-loads in flight per 8-lane group. Ownership, traffic, and layout
// identical to the proven loop; only the add-dependence graph widens.
// ---------------------------------------------------------------------------
__device__ __forceinline__ void gather_quad(const u16x8* __restrict__ f8,
                                            const int* __restrict__ csr_src,
                                            int node, int q, int beg, int end,
                                            float* acc) {
    u16x8 sv = f8[(long long)node * 8 + q];
    float a0[8], a1[8], a2[8], a3[8];
    #pragma unroll
    for (int j = 0; j < 8; ++j) { a0[j] = bf2f(sv[j]); a1[j] = 0.f; a2[j] = 0.f; a3[j] = 0.f; }
    int k = beg;
    for (; k + 4 <= end; k += 4) {
        int s0 = csr_src[k],     s1 = csr_src[k + 1];
        int s2 = csr_src[k + 2], s3 = csr_src[k + 3];
        u16x8 v0 = f8[(long long)s0 * 8 + q];
        u16x8 v1 = f8[(long long)s1 * 8 + q];
        u16x8 v2 = f8[(long long)s2 * 8 + q];
        u16x8 v3 = f8[(long long)s3 * 8 + q];
        #pragma unroll
        for (int j = 0; j < 8; ++j) {
            a0[j] += bf2f(v0[j]);
            a1[j] += bf2f(v1[j]);
            a2[j] += bf2f(v2[j]);
            a3[j] += bf2f(v3[j]);
        }
    }
    for (; k < end; ++k) {
        int s0 = csr_src[k];
        u16x8 v0 = f8[(long long)s0 * 8 + q];
        #pragma unroll
        for (int j = 0; j < 8; ++j) a0[j] += bf2f(v0[j]);
    }
    #pragma unroll
    for (int j = 0; j < 8; ++j) acc[j] = (a0[j] + a1[j]) + (a2[j] + a3[j]);
}

// ---------------------------------------------------------------------------
// Merged prep+part kernel (independent work streams co-scheduled):
//   blocks [0,NBLK_P)            : edge partition into fixed bucket regions
//                                  (LDS counting sort + coalesced int2 flush)
//   blocks [NBLK_P,NBLK_P+NB_G)  : y0 = bf16(x) @ bf16(W1a); zeros xs
//   block  NBLK_P+NB_G           : fragment-prep W1b/W2 + BN consts AB
// cursor zeroed by hipMemsetAsync before launch; reservation adds b*BCAP.
// ---------------------------------------------------------------------------
__global__ __launch_bounds__(256) void prep_kernel(
    const float* __restrict__ x, const int* __restrict__ ei,
    int2* __restrict__ ebuf, int* __restrict__ cursor,
    const float* __restrict__ W1a, unsigned short* __restrict__ y0,
    float* __restrict__ xs,
    const float* __restrict__ W1b, const float* __restrict__ W2,
    unsigned short* __restrict__ w1bp, unsigned short* __restrict__ w2p,
    const float* __restrict__ b1a, const float* __restrict__ g1,
    const float* __restrict__ be1, const float* __restrict__ m1,
    const float* __restrict__ v1,
    const float* __restrict__ b2,  const float* __restrict__ g2,
    const float* __restrict__ be2, const float* __restrict__ m2,
    const float* __restrict__ v2,
    float* __restrict__ AB) {
    __shared__ __align__(16) char smem[CHUNK * 8 + 4096];   // 36 KB union
    int t = threadIdx.x;
    if (blockIdx.x < NBLK_P) {
        // ---- edge partition branch ----
        int* cnt  = (int*)smem;              // 1 KB
        int* cur  = (int*)(smem + 1024);     // 1 KB
        int* goff = (int*)(smem + 2048);     // 1 KB
        int* tmp  = (int*)(smem + 3072);     // 1 KB
        int2* outb = (int2*)(smem + 4096);   // 32 KB staging
        int blk = blockIdx.x;
        int e0 = blk * CHUNK;
        int nE = N_EDGES - e0; if (nE > CHUNK) nE = CHUNK;

        cnt[t] = 0;
        __syncthreads();
        for (int i = t; i < nE; i += 256) {
            unsigned d = (unsigned)ei[N_EDGES + e0 + i];
            atomicAdd(&cnt[__umulhi(d, MAGIC)], 1);
        }
        __syncthreads();
        int s = cnt[t];
        tmp[t] = s;
        __syncthreads();
        for (int off = 1; off < 256; off <<= 1) {
            int a = (t >= off) ? tmp[t - off] : 0;
            __syncthreads();
            tmp[t] += a;
            __syncthreads();
        }
        int lbase = tmp[t] - s;
        int gbase = t * BCAP + atomicAdd(&cursor[t], s);
        cur[t] = lbase;
        goff[t] = gbase - lbase;
        __syncthreads();
        for (int i = t; i < nE; i += 256) {
            int d = ei[N_EDGES + e0 + i];
            int sv = ei[e0 + i];
            int b = __umulhi((unsigned)d, MAGIC);
            int p = atomicAdd(&cur[b], 1);
            outb[p] = (int2){sv, d};
        }
        __syncthreads();
        for (int i = t; i < nE; i += 256) {
            int2 rec = outb[i];
            int b = __umulhi((unsigned)rec.y, MAGIC);
            ebuf[goff[b] + i] = rec;
        }
    } else if (blockIdx.x < NBLK_P + NB_G) {
        // ---- y0 = x@W1a branch ----
        unsigned short* outt = (unsigned short*)smem;   // 8 KB of the union
        int g = blockIdx.x - NBLK_P;
        if (g < (BGRAPHS * DIM) / 256) xs[g * 256 + t] = 0.f;
        int w = t >> 6, lane = t & 63;
        int m = lane & 15, q = lane >> 4;
        int row0 = g * 64 + w * 16;

        bfx8 wa[4][2];
        #pragma unroll
        for (int nt = 0; nt < 4; ++nt)
            #pragma unroll
            for (int kt = 0; kt < 2; ++kt)
                wa[nt][kt] = load_wfrag(W1a, kt, q, nt * 16 + m);

        int rowA = row0 + m;
        if (rowA > N_NODES - 1) rowA = N_NODES - 1;
        const float* xp = x + (long long)rowA * 64;
        bfx8 a0, a1;
        #pragma unroll
        for (int j = 0; j < 8; ++j) {
            a0[j] = (short)f2bf(xp[q * 8 + j]);
            a1[j] = (short)f2bf(xp[32 + q * 8 + j]);
        }
        f32x4 acc[4];
        #pragma unroll
        for (int nt = 0; nt < 4; ++nt) {
            acc[nt] = (f32x4){0.f, 0.f, 0.f, 0.f};
            acc[nt] = __builtin_amdgcn_mfma_f32_16x16x32_bf16(a0, wa[nt][0], acc[nt], 0, 0, 0);
            acc[nt] = __builtin_amdgcn_mfma_f32_16x16x32_bf16(a1, wa[nt][1], acc[nt], 0, 0, 0);
        }
        #pragma unroll
        for (int nt = 0; nt < 4; ++nt)
            #pragma unroll
            for (int r = 0; r < 4; ++r)
                outt[w * 1024 + (q * 4 + r) * 64 + nt * 16 + m] = f2bf(acc[nt][r]);
        __syncthreads();
        #pragma unroll
        for (int i = lane; i < 128; i += 64) {
            int rr = i >> 3, cc = i & 7;   // rr in [0,16) within THIS wave's tile
            int rg = row0 + rr;
            if (rg < N_NODES)
                ((float4*)y0)[(long long)rg * 8 + cc] =
                    *(const float4*)&outt[w * 1024 + rr * 64 + cc * 8];
        }
    } else {
        // ---- fragment-prep W1b, W2; AB constants ----
        const float* Ws[2] = {W1b, W2};
        unsigned short* Wp[2] = {w1bp, w2p};
        #pragma unroll
        for (int wsel = 0; wsel < 2; ++wsel) {
            const float* W = Ws[wsel];
            #pragma unroll
            for (int r = 0; r < 2; ++r) {
                int e = r * 256 + t;           // 0..511
                int kt = e >> 8, q = (e >> 6) & 3, col = e & 63;
                u16x8 o;
                #pragma unroll
                for (int j = 0; j < 8; ++j)
                    o[j] = f2bf(W[(kt * 32 + q * 8 + j) * 64 + col]);
                ((u16x8*)Wp[wsel])[e] = o;
            }
        }
        if (t < 64) {
            float s1 = g1[t] * rsqrtf(v1[t] + BN_EPS);
            AB[t]       = s1;
            AB[64 + t]  = b1a[t] * s1 + (be1[t] - m1[t] * s1);
            float s2 = g2[t] * rsqrtf(v2[t] + BN_EPS);
            AB[128 + t] = s2;
            AB[192 + t] = b2[t] * s2 + (be2[t] - m2[t] * s2);
        }
    }
}

// ---------------------------------------------------------------------------
// Refine: one block per bucket region; LDS counting sort by dst_local;
// coalesced csr_src write; emits rowspan = {begin, end} per node (int2).
// cursor[b] holds bucket SIZE (cursor started at 0).
// ---------------------------------------------------------------------------
__global__ __launch_bounds__(256) void refine_kernel(const int2* __restrict__ ebuf,
                                                     const int* __restrict__ cursor,
                                                     int* __restrict__ csr_src,
                                                     int2* __restrict__ rowspan) {
    __shared__ int cnt[NPB + 1];
    __shared__ int cur[NPB + 1];
    __shared__ int tmp[256];
    __shared__ int outb[BCAP];
    int t = threadIdx.x, b = blockIdx.x;
    int beg = b * BCAP;
    int end = beg + cursor[b];
    int dbase = b * NPB;

    for (int i = t; i < NPB + 1; i += 256) cnt[i] = 0;
    __syncthreads();
    for (int i = beg + t; i < end; i += 256)
        atomicAdd(&cnt[ebuf[i].y - dbase], 1);
    __syncthreads();

    // exclusive scan over NPB entries (2 elems/thread)
    int i0 = 2 * t, i1 = 2 * t + 1;
    int v0 = (i0 < NPB) ? cnt[i0] : 0;
    int v1 = (i1 < NPB) ? cnt[i1] : 0;
    int s = v0 + v1;
    tmp[t] = s;
    __syncthreads();
    for (int off = 1; off < 256; off <<= 1) {
        int a = (t >= off) ? tmp[t - off] : 0;
        __syncthreads();
        tmp[t] += a;
        __syncthreads();
    }
    int excl = tmp[t] - s;
    if (i0 < NPB) cur[i0] = excl;
    if (i1 < NPB) cur[i1] = excl + v0;
    {
        int g0 = dbase + i0;
        if (i0 < NPB && g0 < N_NODES)
            rowspan[g0] = (int2){beg + excl, beg + excl + v0};
        int g1 = dbase + i1;
        if (i1 < NPB && g1 < N_NODES)
            rowspan[g1] = (int2){beg + excl + v0, beg + excl + v0 + v1};
    }
    __syncthreads();

    for (int i = beg + t; i < end; i += 256) {
        int2 rec = ebuf[i];
        int dl = rec.y - dbase;
        int pos = atomicAdd(&cur[dl], 1);
        if (pos < BCAP) outb[pos] = rec.x;
    }
    __syncthreads();

    int nb = end - beg; if (nb > BCAP) nb = BCAP;
    for (int i = t; i < nb; i += 256) csr_src[beg + i] = outb[i];
}

// ---------------------------------------------------------------------------
// Fused agg1 + BN1 + ReLU + MLP: per block of 32 nodes,
//   h1 = relu(A1*agg(y0)+B1)          (quad-acc gather, same ownership)
//   h2 = relu(h1 @ W1b + b1b)         (LDS-staged MFMA)
//   y2 = h2 @ W2
// ---------------------------------------------------------------------------
__global__ __launch_bounds__(256) void gather_mlp1_kernel(
    const unsigned short* __restrict__ feat,
    const int2* __restrict__ rowspan,
    const int* __restrict__ csr_src,
    const float* __restrict__ AB,
    const unsigned short* __restrict__ w1bp, const float* __restrict__ b1b,
    const unsigned short* __restrict__ w2p,
    unsigned short* __restrict__ y2) {
    __shared__ unsigned short h1t[32 * 72];
    __shared__ unsigned short h2t[32 * 72];
    __shared__ unsigned short outt[32 * 64];

    int t = threadIdx.x;
    int nl = t >> 3, q8 = t & 7;
    int node = blockIdx.x * 32 + nl;
    const u16x8* f8 = (const u16x8*)feat;
    {
        int2 rs = rowspan[node];
        float acc[8];
        gather_quad(f8, csr_src, node, q8, rs.x, rs.y, acc);
        #pragma unroll
        for (int j = 0; j < 8; ++j) {
            int c = q8 * 8 + j;
            h1t[nl * 72 + c] = f2bf(fmaxf(acc[j] * AB[c] + AB[64 + c], 0.f));
        }
    }
    __syncthreads();

    // MFMA phase: wave w owns row-tile rt=w>>1 (16 rows), col-tiles c0,c0+1
    int w = t >> 6, lane = t & 63;
    int m = lane & 15, q = lane >> 4;
    int rt = w >> 1;
    int c0 = (w & 1) * 2;

    const bfx8* wbp = (const bfx8*)w1bp;
    const bfx8* wcp = (const bfx8*)w2p;

    {
        const bfx8* hp = (const bfx8*)&h1t[(rt * 16 + m) * 72];
        bfx8 a0 = hp[q];
        bfx8 a1 = hp[4 + q];
        #pragma unroll
        for (int ci = 0; ci < 2; ++ci) {
            int ct = c0 + ci;
            bfx8 w0 = wbp[(0 * 4 + q) * 64 + ct * 16 + m];
            bfx8 w1 = wbp[(1 * 4 + q) * 64 + ct * 16 + m];
            f32x4 acc = (f32x4){0.f, 0.f, 0.f, 0.f};
            acc = __builtin_amdgcn_mfma_f32_16x16x32_bf16(a0, w0, acc, 0, 0, 0);
            acc = __builtin_amdgcn_mfma_f32_16x16x32_bf16(a1, w1, acc, 0, 0, 0);
            float bb = b1b[ct * 16 + m];
            #pragma unroll
            for (int r = 0; r < 4; ++r)
                h2t[(rt * 16 + q * 4 + r) * 72 + ct * 16 + m] = f2bf(fmaxf(acc[r] + bb, 0.f));
        }
    }
    __syncthreads();

    {
        const bfx8* hp = (const bfx8*)&h2t[(rt * 16 + m) * 72];
        bfx8 a0 = hp[q];
        bfx8 a1 = hp[4 + q];
        #pragma unroll
        for (int ci = 0; ci < 2; ++ci) {
            int ct = c0 + ci;
            bfx8 w0 = wcp[(0 * 4 + q) * 64 + ct * 16 + m];
            bfx8 w1 = wcp[(1 * 4 + q) * 64 + ct * 16 + m];
            f32x4 acc = (f32x4){0.f, 0.f, 0.f, 0.f};
            acc = __builtin_amdgcn_mfma_f32_16x16x32_bf16(a0, w0, acc, 0, 0, 0);
            acc = __builtin_amdgcn_mfma_f32_16x16x32_bf16(a1, w1, acc, 0, 0, 0);
            #pragma unroll
            for (int r = 0; r < 4; ++r)
                outt[(rt * 16 + q * 4 + r) * 64 + ct * 16 + m] = f2bf(acc[r]);
        }
    }
    __syncthreads();

    // coalesced store: one float4 (8 bf16) per thread
    int rr = t >> 3, cc = t & 7;
    ((float4*)y2)[((long long)blockIdx.x * 32 + rr) * 8 + cc] =
        *(const float4*)&outt[rr * 64 + cc * 8];
}

// ---------------------------------------------------------------------------
// gather + BN2 + ReLU + pool: h4 = relu(A2*(y2[i]+sum y2[src])+B2);
// xs[batch[i]] += h4. Segmented LDS pool.
// ---------------------------------------------------------------------------
__global__ __launch_bounds__(256) void gather_pool_kernel(
    const unsigned short* __restrict__ feat,
    const int2* __restrict__ rowspan,
    const int* __restrict__ csr_src,
    const float* __restrict__ AB, const int* __restrict__ batch,
    float* __restrict__ xs) {
    __shared__ float h4[32 * 65];
    __shared__ int bts[32];
    int t = threadIdx.x;
    int nl = t >> 3;                 // 0..31 local node
    int q = t & 7;
    int node = blockIdx.x * 32 + nl;
    if (t < 32) bts[t] = batch[blockIdx.x * 32 + t];
    const u16x8* f8 = (const u16x8*)feat;
    int2 rs = rowspan[node];
    float acc[8];
    gather_quad(f8, csr_src, node, q, rs.x, rs.y, acc);
    #pragma unroll
    for (int j = 0; j < 8; ++j) {
        int c = q * 8 + j;
        h4[nl * 65 + c] = fmaxf(acc[j] * AB[128 + c] + AB[192 + c], 0.f);
    }
    __syncthreads();

    int col = t & 63;
    int r0 = (t >> 6) * 8;
    int cb = bts[r0];
    float cur = 0.f;
    #pragma unroll
    for (int r = 0; r < 8; ++r) {
        int b = bts[r0 + r];
        if (b != cb) {
            unsafeAtomicAdd(&xs[cb * 64 + col], cur);
            cb = b;
            cur = 0.f;
        }
        cur += h4[(r0 + r) * 65 + col];
    }
    unsafeAtomicAdd(&xs[cb * 64 + col], cur);
}

// ---------------------------------------------------------------------------
// Head: x_topo = relu(topo @ Wt + bt); out = [x_struct, x_topo] @ Wc + bc
// ---------------------------------------------------------------------------
__global__ __launch_bounds__(64) void head_kernel(
    const float* __restrict__ xs, const float* __restrict__ topo,
    const float* __restrict__ Wt, const float* __restrict__ bt,
    const float* __restrict__ Wc, const float* __restrict__ bc,
    float* __restrict__ out) {
    __shared__ float trow[64];
    __shared__ float comb[128];
    int b = blockIdx.x;
    int h = threadIdx.x;
    trow[h] = topo[b * 64 + h];
    __syncthreads();
    float acc = bt[h];
    #pragma unroll
    for (int k = 0; k < 64; ++k) acc += trow[k] * Wt[k * 64 + h];
    comb[h] = xs[b * 64 + h];
    comb[64 + h] = fmaxf(acc, 0.f);
    __syncthreads();
    if (h < NCLASS) {
        float o = bc[h];
        #pragma unroll
        for (int k = 0; k < 128; ++k) o += comb[k] * Wc[k * NCLASS + h];
        out[b * NCLASS + h] = o;
    }
}

// ---------------------------------------------------------------------------
extern "C" void kernel_launch(void* const* d_in, const int* in_sizes, int n_in,
                              void* d_out, int out_size, void* d_ws, size_t ws_size,
                              hipStream_t stream) {
    const float* x     = (const float*)d_in[0];
    const int*   ei    = (const int*)d_in[1];
    const int*   batch = (const int*)d_in[2];
    const float* topo  = (const float*)d_in[3];
    const float* W1a   = (const float*)d_in[4];
    const float* b1a   = (const float*)d_in[5];
    const float* g1    = (const float*)d_in[6];
    const float* be1   = (const float*)d_in[7];
    const float* m1    = (const float*)d_in[8];
    const float* v1    = (const float*)d_in[9];
    const float* W1b   = (const float*)d_in[10];
    const float* b1b   = (const float*)d_in[11];
    const float* W2    = (const float*)d_in[12];
    const float* b2    = (const float*)d_in[13];
    const float* g2    = (const float*)d_in[14];
    const float* be2   = (const float*)d_in[15];
    const float* m2    = (const float*)d_in[16];
    const float* v2    = (const float*)d_in[17];
    const float* Wt    = (const float*)d_in[18];
    const float* bt    = (const float*)d_in[19];
    const float* Wc    = (const float*)d_in[20];
    const float* bc    = (const float*)d_in[21];
    float* out = (float*)d_out;

    // Workspace layout (16B-aligned chunks)
    char* p = (char*)d_ws;
    unsigned short* y0   = (unsigned short*)p; p += (size_t)N_NODES * DIM * 2;  // 12.8 MB
    unsigned short* y2b  = (unsigned short*)p; p += (size_t)N_NODES * DIM * 2;  // 12.8 MB
    float* xs      = (float*)p; p += (size_t)BGRAPHS * DIM * 4;                 // 256 KB
    int2*  rowspan = (int2*)p;  p += (size_t)(N_NODES + 16) * 8;                // 800 KB
    int*   cursor  = (int*)p;   p += 1024;                                      // 256 ints
    unsigned short* w1bp = (unsigned short*)p; p += 512 * 16;                   // 8 KB
    unsigned short* w2p  = (unsigned short*)p; p += 512 * 16;                   // 8 KB
    float* AB      = (float*)p; p += 256 * 4;                                   // 1 KB
    int2*  ebuf    = (int2*)p;  p += (size_t)NBUCK * BCAP * 8;                  // 16.8 MB
    int*   csr_src = (int*)p;                                                   // 8.4 MB

    // 0) zero the bucket cursors (stream-ordered, graph-capturable)
    hipMemsetAsync(cursor, 0, NBUCK * sizeof(int), stream);
    // 1) merged: edge partition  ||  y0 = x@W1a  ||  weight/BN-const prep
    prep_kernel<<<NBLK_P + NB_G + 1, 256, 0, stream>>>(
        x, ei, ebuf, cursor, W1a, y0, xs, W1b, W2, w1bp, w2p,
        b1a, g1, be1, m1, v1, b2, g2, be2, m2, v2, AB);
    // 2) per-bucket counting sort -> csr_src + rowspan
    refine_kernel<<<NBUCK, 256, 0, stream>>>(ebuf, cursor, csr_src, rowspan);
    // 3) fused agg1+BN1+ReLU + MLP (h1,h2 in LDS): y2 = relu(h1@W1b+b1b)@W2
    gather_mlp1_kernel<<<N_NODES / 32, 256, 0, stream>>>(
        y0, rowspan, csr_src, AB, w1bp, b1b, w2p, y2b);
    // 4) agg2 + BN2 + ReLU + pool
    gather_pool_kernel<<<N_NODES / 32, 256, 0, stream>>>(
        y2b, rowspan, csr_src, AB, batch, xs);
    // 5) head
    head_kernel<<<BGRAPHS, 64, 0, stream>>>(xs, topo, Wt, bt, Wc, bc, out);
}

// Round 17
// 205.556 us; speedup vs baseline: 1.0250x; 1.0250x over previous
//
#include <hip/hip_runtime.h>

// Problem constants (match reference)
#define N_NODES 100000
#define N_EDGES 1200000
#define DIM     64
#define BGRAPHS 1000
#define NCLASS  10
#define BN_EPS  1e-5f

// CSR-build partition constants
#define NBUCK   256            // coarse buckets
#define NPB     391            // nodes per bucket (256*391 = 100096 >= N)
#define MAGIC   10984572u      // ceil(2^32/391): bucket = umulhi(d, MAGIC)
#define CHUNK   4096           // edges per partition block (32KB int2 staging)
#define NBLK_P  293            // ceil(E / CHUNK)
#define BCAP    8192           // fixed per-bucket region capacity (proven >= max bucket size)
#define NB_G    1563           // ceil(N/64) GEMM blocks in prep

typedef __attribute__((ext_vector_type(8))) short   bfx8;   // 8 bf16 MFMA A/B frag
typedef __attribute__((ext_vector_type(4))) float   f32x4;  // MFMA C/D frag
typedef __attribute__((ext_vector_type(8))) unsigned short u16x8;

__device__ __forceinline__ unsigned short f2bf(float f) {
    unsigned u = __builtin_bit_cast(unsigned, f);
    unsigned r = (u + 0x7FFFu + ((u >> 16) & 1u)) >> 16;   // RNE
    return (unsigned short)r;
}
__device__ __forceinline__ float bf2f(unsigned short h) {
    unsigned u = ((unsigned)h) << 16;
    return __builtin_bit_cast(float, u);
}

// B-fragment loader: element j = W[(kt*32 + q*8 + j)][col]  (fp32 W -> bf16)
__device__ __forceinline__ bfx8 load_wfrag(const float* __restrict__ W, int kt, int q, int col) {
    bfx8 f;
    #pragma unroll
    for (int j = 0; j < 8; ++j)
        f[j] = (short)f2bf(W[(kt * 32 + q * 8 + j) * 64 + col]);
    return f;
}

// ---------------------------------------------------------------------------
// Dual-accumulator gather core: self + even/odd neighbor chains (independent
// fp32 add chains keep 2 row-loads in flight per 8-lane group). Proven ILP
// optimum: single-chain (r14) and quad-chain (r16) both measure slower.
// ---------------------------------------------------------------------------
__device__ __forceinline__ void gather_dual(const u16x8* __restrict__ f8,
                                            const int* __restrict__ csr_src,
                                            int node, int q, int beg, int end,
                                            float* acc) {
    u16x8 sv = f8[(long long)node * 8 + q];
    float acca[8], accb[8];
    #pragma unroll
    for (int j = 0; j < 8; ++j) { acca[j] = bf2f(sv[j]); accb[j] = 0.f; }
    int k = beg;
    for (; k + 2 <= end; k += 2) {
        int s0 = csr_src[k], s1 = csr_src[k + 1];
        u16x8 v0 = f8[(long long)s0 * 8 + q];
        u16x8 v1 = f8[(long long)s1 * 8 + q];
        #pragma unroll
        for (int j = 0; j < 8; ++j) {
            acca[j] += bf2f(v0[j]);
            accb[j] += bf2f(v1[j]);
        }
    }
    if (k < end) {
        int s0 = csr_src[k];
        u16x8 v0 = f8[(long long)s0 * 8 + q];
        #pragma unroll
        for (int j = 0; j < 8; ++j) acca[j] += bf2f(v0[j]);
    }
    #pragma unroll
    for (int j = 0; j < 8; ++j) acc[j] = acca[j] + accb[j];
}

// ---------------------------------------------------------------------------
// Merged prep+part kernel (independent work streams co-scheduled):
//   blocks [0,NBLK_P)            : edge partition into fixed bucket regions
//                                  (LDS counting sort + coalesced int2 flush)
//   blocks [NBLK_P,NBLK_P+NB_G)  : y0 = bf16(x) @ bf16(W1a); zeros xs
//   block  NBLK_P+NB_G           : fragment-prep W1b/W2 + BN consts AB
// cursor zeroed by hipMemsetAsync before launch; reservation adds b*BCAP.
// ---------------------------------------------------------------------------
__global__ __launch_bounds__(256) void prep_kernel(
    const float* __restrict__ x, const int* __restrict__ ei,
    int2* __restrict__ ebuf, int* __restrict__ cursor,
    const float* __restrict__ W1a, unsigned short* __restrict__ y0,
    float* __restrict__ xs,
    const float* __restrict__ W1b, const float* __restrict__ W2,
    unsigned short* __restrict__ w1bp, unsigned short* __restrict__ w2p,
    const float* __restrict__ b1a, const float* __restrict__ g1,
    const float* __restrict__ be1, const float* __restrict__ m1,
    const float* __restrict__ v1,
    const float* __restrict__ b2,  const float* __restrict__ g2,
    const float* __restrict__ be2, const float* __restrict__ m2,
    const float* __restrict__ v2,
    float* __restrict__ AB) {
    __shared__ __align__(16) char smem[CHUNK * 8 + 4096];   // 36 KB union
    int t = threadIdx.x;
    if (blockIdx.x < NBLK_P) {
        // ---- edge partition branch ----
        int* cnt  = (int*)smem;              // 1 KB
        int* cur  = (int*)(smem + 1024);     // 1 KB
        int* goff = (int*)(smem + 2048);     // 1 KB
        int* tmp  = (int*)(smem + 3072);     // 1 KB
        int2* outb = (int2*)(smem + 4096);   // 32 KB staging
        int blk = blockIdx.x;
        int e0 = blk * CHUNK;
        int nE = N_EDGES - e0; if (nE > CHUNK) nE = CHUNK;

        cnt[t] = 0;
        __syncthreads();
        for (int i = t; i < nE; i += 256) {
            unsigned d = (unsigned)ei[N_EDGES + e0 + i];
            atomicAdd(&cnt[__umulhi(d, MAGIC)], 1);
        }
        __syncthreads();
        int s = cnt[t];
        tmp[t] = s;
        __syncthreads();
        for (int off = 1; off < 256; off <<= 1) {
            int a = (t >= off) ? tmp[t - off] : 0;
            __syncthreads();
            tmp[t] += a;
            __syncthreads();
        }
        int lbase = tmp[t] - s;
        int gbase = t * BCAP + atomicAdd(&cursor[t], s);
        cur[t] = lbase;
        goff[t] = gbase - lbase;
        __syncthreads();
        for (int i = t; i < nE; i += 256) {
            int d = ei[N_EDGES + e0 + i];
            int sv = ei[e0 + i];
            int b = __umulhi((unsigned)d, MAGIC);
            int p = atomicAdd(&cur[b], 1);
            outb[p] = (int2){sv, d};
        }
        __syncthreads();
        for (int i = t; i < nE; i += 256) {
            int2 rec = outb[i];
            int b = __umulhi((unsigned)rec.y, MAGIC);
            ebuf[goff[b] + i] = rec;
        }
    } else if (blockIdx.x < NBLK_P + NB_G) {
        // ---- y0 = x@W1a branch ----
        unsigned short* outt = (unsigned short*)smem;   // 8 KB of the union
        int g = blockIdx.x - NBLK_P;
        if (g < (BGRAPHS * DIM) / 256) xs[g * 256 + t] = 0.f;
        int w = t >> 6, lane = t & 63;
        int m = lane & 15, q = lane >> 4;
        int row0 = g * 64 + w * 16;

        bfx8 wa[4][2];
        #pragma unroll
        for (int nt = 0; nt < 4; ++nt)
            #pragma unroll
            for (int kt = 0; kt < 2; ++kt)
                wa[nt][kt] = load_wfrag(W1a, kt, q, nt * 16 + m);

        int rowA = row0 + m;
        if (rowA > N_NODES - 1) rowA = N_NODES - 1;
        const float* xp = x + (long long)rowA * 64;
        bfx8 a0, a1;
        #pragma unroll
        for (int j = 0; j < 8; ++j) {
            a0[j] = (short)f2bf(xp[q * 8 + j]);
            a1[j] = (short)f2bf(xp[32 + q * 8 + j]);
        }
        f32x4 acc[4];
        #pragma unroll
        for (int nt = 0; nt < 4; ++nt) {
            acc[nt] = (f32x4){0.f, 0.f, 0.f, 0.f};
            acc[nt] = __builtin_amdgcn_mfma_f32_16x16x32_bf16(a0, wa[nt][0], acc[nt], 0, 0, 0);
            acc[nt] = __builtin_amdgcn_mfma_f32_16x16x32_bf16(a1, wa[nt][1], acc[nt], 0, 0, 0);
        }
        #pragma unroll
        for (int nt = 0; nt < 4; ++nt)
            #pragma unroll
            for (int r = 0; r < 4; ++r)
                outt[w * 1024 + (q * 4 + r) * 64 + nt * 16 + m] = f2bf(acc[nt][r]);
        __syncthreads();
        #pragma unroll
        for (int i = lane; i < 128; i += 64) {
            int rr = i >> 3, cc = i & 7;   // rr in [0,16) within THIS wave's tile
            int rg = row0 + rr;
            if (rg < N_NODES)
                ((float4*)y0)[(long long)rg * 8 + cc] =
                    *(const float4*)&outt[w * 1024 + rr * 64 + cc * 8];
        }
    } else {
        // ---- fragment-prep W1b, W2; AB constants ----
        const float* Ws[2] = {W1b, W2};
        unsigned short* Wp[2] = {w1bp, w2p};
        #pragma unroll
        for (int wsel = 0; wsel < 2; ++wsel) {
            const float* W = Ws[wsel];
            #pragma unroll
            for (int r = 0; r < 2; ++r) {
                int e = r * 256 + t;           // 0..511
                int kt = e >> 8, q = (e >> 6) & 3, col = e & 63;
                u16x8 o;
                #pragma unroll
                for (int j = 0; j < 8; ++j)
                    o[j] = f2bf(W[(kt * 32 + q * 8 + j) * 64 + col]);
                ((u16x8*)Wp[wsel])[e] = o;
            }
        }
        if (t < 64) {
            float s1 = g1[t] * rsqrtf(v1[t] + BN_EPS);
            AB[t]       = s1;
            AB[64 + t]  = b1a[t] * s1 + (be1[t] - m1[t] * s1);
            float s2 = g2[t] * rsqrtf(v2[t] + BN_EPS);
            AB[128 + t] = s2;
            AB[192 + t] = b2[t] * s2 + (be2[t] - m2[t] * s2);
        }
    }
}

// ---------------------------------------------------------------------------
// Refine: one block per bucket region; LDS counting sort by dst_local;
// coalesced csr_src write; emits rowspan = {begin, end} per node (int2).
// cursor[b] holds bucket SIZE (cursor started at 0).
// ---------------------------------------------------------------------------
__global__ __launch_bounds__(256) void refine_kernel(const int2* __restrict__ ebuf,
                                                     const int* __restrict__ cursor,
                                                     int* __restrict__ csr_src,
                                                     int2* __restrict__ rowspan) {
    __shared__ int cnt[NPB + 1];
    __shared__ int cur[NPB + 1];
    __shared__ int tmp[256];
    __shared__ int outb[BCAP];
    int t = threadIdx.x, b = blockIdx.x;
    int beg = b * BCAP;
    int end = beg + cursor[b];
    int dbase = b * NPB;

    for (int i = t; i < NPB + 1; i += 256) cnt[i] = 0;
    __syncthreads();
    for (int i = beg + t; i < end; i += 256)
        atomicAdd(&cnt[ebuf[i].y - dbase], 1);
    __syncthreads();

    // exclusive scan over NPB entries (2 elems/thread)
    int i0 = 2 * t, i1 = 2 * t + 1;
    int v0 = (i0 < NPB) ? cnt[i0] : 0;
    int v1 = (i1 < NPB) ? cnt[i1] : 0;
    int s = v0 + v1;
    tmp[t] = s;
    __syncthreads();
    for (int off = 1; off < 256; off <<= 1) {
        int a = (t >= off) ? tmp[t - off] : 0;
        __syncthreads();
        tmp[t] += a;
        __syncthreads();
    }
    int excl = tmp[t] - s;
    if (i0 < NPB) cur[i0] = excl;
    if (i1 < NPB) cur[i1] = excl + v0;
    {
        int g0 = dbase + i0;
        if (i0 < NPB && g0 < N_NODES)
            rowspan[g0] = (int2){beg + excl, beg + excl + v0};
        int g1 = dbase + i1;
        if (i1 < NPB && g1 < N_NODES)
            rowspan[g1] = (int2){beg + excl + v0, beg + excl + v0 + v1};
    }
    __syncthreads();

    for (int i = beg + t; i < end; i += 256) {
        int2 rec = ebuf[i];
        int dl = rec.y - dbase;
        int pos = atomicAdd(&cur[dl], 1);
        if (pos < BCAP) outb[pos] = rec.x;
    }
    __syncthreads();

    int nb = end - beg; if (nb > BCAP) nb = BCAP;
    for (int i = t; i < nb; i += 256) csr_src[beg + i] = outb[i];
}

// ---------------------------------------------------------------------------
// Fused agg1 + BN1 + ReLU + MLP: per block of 32 nodes,
//   h1 = relu(A1*agg(y0)+B1)          (dual-acc gather, same ownership)
//   h2 = relu(h1 @ W1b + b1b)         (LDS-staged MFMA)
//   y2 = h2 @ W2
// ---------------------------------------------------------------------------
__global__ __launch_bounds__(256) void gather_mlp1_kernel(
    const unsigned short* __restrict__ feat,
    const int2* __restrict__ rowspan,
    const int* __restrict__ csr_src,
    const float* __restrict__ AB,
    const unsigned short* __restrict__ w1bp, const float* __restrict__ b1b,
    const unsigned short* __restrict__ w2p,
    unsigned short* __restrict__ y2) {
    __shared__ unsigned short h1t[32 * 72];
    __shared__ unsigned short h2t[32 * 72];
    __shared__ unsigned short outt[32 * 64];

    int t = threadIdx.x;
    int nl = t >> 3, q8 = t & 7;
    int node = blockIdx.x * 32 + nl;
    const u16x8* f8 = (const u16x8*)feat;
    {
        int2 rs = rowspan[node];
        float acc[8];
        gather_dual(f8, csr_src, node, q8, rs.x, rs.y, acc);
        #pragma unroll
        for (int j = 0; j < 8; ++j) {
            int c = q8 * 8 + j;
            h1t[nl * 72 + c] = f2bf(fmaxf(acc[j] * AB[c] + AB[64 + c], 0.f));
        }
    }
    __syncthreads();

    // MFMA phase: wave w owns row-tile rt=w>>1 (16 rows), col-tiles c0,c0+1
    int w = t >> 6, lane = t & 63;
    int m = lane & 15, q = lane >> 4;
    int rt = w >> 1;
    int c0 = (w & 1) * 2;

    const bfx8* wbp = (const bfx8*)w1bp;
    const bfx8* wcp = (const bfx8*)w2p;

    {
        const bfx8* hp = (const bfx8*)&h1t[(rt * 16 + m) * 72];
        bfx8 a0 = hp[q];
        bfx8 a1 = hp[4 + q];
        #pragma unroll
        for (int ci = 0; ci < 2; ++ci) {
            int ct = c0 + ci;
            bfx8 w0 = wbp[(0 * 4 + q) * 64 + ct * 16 + m];
            bfx8 w1 = wbp[(1 * 4 + q) * 64 + ct * 16 + m];
            f32x4 acc = (f32x4){0.f, 0.f, 0.f, 0.f};
            acc = __builtin_amdgcn_mfma_f32_16x16x32_bf16(a0, w0, acc, 0, 0, 0);
            acc = __builtin_amdgcn_mfma_f32_16x16x32_bf16(a1, w1, acc, 0, 0, 0);
            float bb = b1b[ct * 16 + m];
            #pragma unroll
            for (int r = 0; r < 4; ++r)
                h2t[(rt * 16 + q * 4 + r) * 72 + ct * 16 + m] = f2bf(fmaxf(acc[r] + bb, 0.f));
        }
    }
    __syncthreads();

    {
        const bfx8* hp = (const bfx8*)&h2t[(rt * 16 + m) * 72];
        bfx8 a0 = hp[q];
        bfx8 a1 = hp[4 + q];
        #pragma unroll
        for (int ci = 0; ci < 2; ++ci) {
            int ct = c0 + ci;
            bfx8 w0 = wcp[(0 * 4 + q) * 64 + ct * 16 + m];
            bfx8 w1 = wcp[(1 * 4 + q) * 64 + ct * 16 + m];
            f32x4 acc = (f32x4){0.f, 0.f, 0.f, 0.f};
            acc = __builtin_amdgcn_mfma_f32_16x16x32_bf16(a0, w0, acc, 0, 0, 0);
            acc = __builtin_amdgcn_mfma_f32_16x16x32_bf16(a1, w1, acc, 0, 0, 0);
            #pragma unroll
            for (int r = 0; r < 4; ++r)
                outt[(rt * 16 + q * 4 + r) * 64 + ct * 16 + m] = f2bf(acc[r]);
        }
    }
    __syncthreads();

    // coalesced store: one float4 (8 bf16) per thread
    int rr = t >> 3, cc = t & 7;
    ((float4*)y2)[((long long)blockIdx.x * 32 + rr) * 8 + cc] =
        *(const float4*)&outt[rr * 64 + cc * 8];
}

// ---------------------------------------------------------------------------
// gather + BN2 + ReLU + pool: h4 = relu(A2*(y2[i]+sum y2[src])+B2);
// xs[batch[i]] += h4. Segmented LDS pool.
// ---------------------------------------------------------------------------
__global__ __launch_bounds__(256) void gather_pool_kernel(
    const unsigned short* __restrict__ feat,
    const int2* __restrict__ rowspan,
    const int* __restrict__ csr_src,
    const float* __restrict__ AB, const int* __restrict__ batch,
    float* __restrict__ xs) {
    __shared__ float h4[32 * 65];
    __shared__ int bts[32];
    int t = threadIdx.x;
    int nl = t >> 3;                 // 0..31 local node
    int q = t & 7;
    int node = blockIdx.x * 32 + nl;
    if (t < 32) bts[t] = batch[blockIdx.x * 32 + t];
    const u16x8* f8 = (const u16x8*)feat;
    int2 rs = rowspan[node];
    float acc[8];
    gather_dual(f8, csr_src, node, q, rs.x, rs.y, acc);
    #pragma unroll
    for (int j = 0; j < 8; ++j) {
        int c = q * 8 + j;
        h4[nl * 65 + c] = fmaxf(acc[j] * AB[128 + c] + AB[192 + c], 0.f);
    }
    __syncthreads();

    int col = t & 63;
    int r0 = (t >> 6) * 8;
    int cb = bts[r0];
    float cur = 0.f;
    #pragma unroll
    for (int r = 0; r < 8; ++r) {
        int b = bts[r0 + r];
        if (b != cb) {
            unsafeAtomicAdd(&xs[cb * 64 + col], cur);
            cb = b;
            cur = 0.f;
        }
        cur += h4[(r0 + r) * 65 + col];
    }
    unsafeAtomicAdd(&xs[cb * 64 + col], cur);
}

// ---------------------------------------------------------------------------
// Head: x_topo = relu(topo @ Wt + bt); out = [x_struct, x_topo] @ Wc + bc
// ---------------------------------------------------------------------------
__global__ __launch_bounds__(64) void head_kernel(
    const float* __restrict__ xs, const float* __restrict__ topo,
    const float* __restrict__ Wt, const float* __restrict__ bt,
    const float* __restrict__ Wc, const float* __restrict__ bc,
    float* __restrict__ out) {
    __shared__ float trow[64];
    __shared__ float comb[128];
    int b = blockIdx.x;
    int h = threadIdx.x;
    trow[h] = topo[b * 64 + h];
    __syncthreads();
    float acc = bt[h];
    #pragma unroll
    for (int k = 0; k < 64; ++k) acc += trow[k] * Wt[k * 64 + h];
    comb[h] = xs[b * 64 + h];
    comb[64 + h] = fmaxf(acc, 0.f);
    __syncthreads();
    if (h < NCLASS) {
        float o = bc[h];
        #pragma unroll
        for (int k = 0; k < 128; ++k) o += comb[k] * Wc[k * NCLASS + h];
        out[b * NCLASS + h] = o;
    }
}

// ---------------------------------------------------------------------------
extern "C" void kernel_launch(void* const* d_in, const int* in_sizes, int n_in,
                              void* d_out, int out_size, void* d_ws, size_t ws_size,
                              hipStream_t stream) {
    const float* x     = (const float*)d_in[0];
    const int*   ei    = (const int*)d_in[1];
    const int*   batch = (const int*)d_in[2];
    const float* topo  = (const float*)d_in[3];
    const float* W1a   = (const float*)d_in[4];
    const float* b1a   = (const float*)d_in[5];
    const float* g1    = (const float*)d_in[6];
    const float* be1   = (const float*)d_in[7];
    const float* m1    = (const float*)d_in[8];
    const float* v1    = (const float*)d_in[9];
    const float* W1b   = (const float*)d_in[10];
    const float* b1b   = (const float*)d_in[11];
    const float* W2    = (const float*)d_in[12];
    const float* b2    = (const float*)d_in[13];
    const float* g2    = (const float*)d_in[14];
    const float* be2   = (const float*)d_in[15];
    const float* m2    = (const float*)d_in[16];
    const float* v2    = (const float*)d_in[17];
    const float* Wt    = (const float*)d_in[18];
    const float* bt    = (const float*)d_in[19];
    const float* Wc    = (const float*)d_in[20];
    const float* bc    = (const float*)d_in[21];
    float* out = (float*)d_out;

    // Workspace layout (16B-aligned chunks)
    char* p = (char*)d_ws;
    unsigned short* y0   = (unsigned short*)p; p += (size_t)N_NODES * DIM * 2;  // 12.8 MB
    unsigned short* y2b  = (unsigned short*)p; p += (size_t)N_NODES * DIM * 2;  // 12.8 MB
    float* xs      = (float*)p; p += (size_t)BGRAPHS * DIM * 4;                 // 256 KB
    int2*  rowspan = (int2*)p;  p += (size_t)(N_NODES + 16) * 8;                // 800 KB
    int*   cursor  = (int*)p;   p += 1024;                                      // 256 ints
    unsigned short* w1bp = (unsigned short*)p; p += 512 * 16;                   // 8 KB
    unsigned short* w2p  = (unsigned short*)p; p += 512 * 16;                   // 8 KB
    float* AB      = (float*)p; p += 256 * 4;                                   // 1 KB
    int2*  ebuf    = (int2*)p;  p += (size_t)NBUCK * BCAP * 8;                  // 16.8 MB
    int*   csr_src = (int*)p;                                                   // 8.4 MB

    // 0) zero the bucket cursors (stream-ordered, graph-capturable)
    hipMemsetAsync(cursor, 0, NBUCK * sizeof(int), stream);
    // 1) merged: edge partition  ||  y0 = x@W1a  ||  weight/BN-const prep
    prep_kernel<<<NBLK_P + NB_G + 1, 256, 0, stream>>>(
        x, ei, ebuf, cursor, W1a, y0, xs, W1b, W2, w1bp, w2p,
        b1a, g1, be1, m1, v1, b2, g2, be2, m2, v2, AB);
    // 2) per-bucket counting sort -> csr_src + rowspan
    refine_kernel<<<NBUCK, 256, 0, stream>>>(ebuf, cursor, csr_src, rowspan);
    // 3) fused agg1+BN1+ReLU + MLP (h1,h2 in LDS): y2 = relu(h1@W1b+b1b)@W2
    gather_mlp1_kernel<<<N_NODES / 32, 256, 0, stream>>>(
        y0, rowspan, csr_src, AB, w1bp, b1b, w2p, y2b);
    // 4) agg2 + BN2 + ReLU + pool
    gather_pool_kernel<<<N_NODES / 32, 256, 0, stream>>>(
        y2b, rowspan, csr_src, AB, batch, xs);
    // 5) head
    head_kernel<<<BGRAPHS, 64, 0, stream>>>(xs, topo, Wt, bt, Wc, bc, out);
}